// Round 8
// baseline (162.248 us; speedup 1.0000x reference)
//
#include <hip/hip_runtime.h>

#define PI_D 3.14159265358979323846

#define BATCH   64
#define LWAV    160000
#define NFFT    2048
#define HOP     512
#define NMELS   128
#define NFRAMES 313      // 1 + 160000/512
#define NCPLX   1024     // complex FFT size (real-pack)
#define PADW    1024     // NFFT/2

// PCEN chunked scan
#define NCH     16
#define CHLEN   20       // 15*20 + 13 = 313

// workspace layout (float offsets)
#define OFF_WIN  0        // 2048 window (natural order, read as float2)
#define OFF_LEN  2048     // 128 ints: CSR length per mel
#define OFF_KK   2176     // int[65][128]: bin index, entry-major
#define OFF_WW   10496    // float[65][128]: weight
#define OFF_MFIN 18816    // 64*16*128 chunk-local final EMA states
#define OFF_MEL  149888   // NFRAMES * BATCH * NMELS (t-major mel buffer)

#define SW4(u) ((((u)&3)<<2)|((u)>>2))   // base-4 digit swap of 4-bit index
#define CMULC(xr, xi, cr, ci) { float _t = (xr); (xr) = _t*(cr) - (xi)*(ci); (xi) = _t*(ci) + (xi)*(cr); }
#define WVB() { __builtin_amdgcn_wave_barrier(); asm volatile("" ::: "memory"); }

__device__ __forceinline__ double melpt(int i) {
    double mlo = 2595.0 * log10(1.0 + 20.0 / 700.0);
    double mhi = 2595.0 * log10(1.0 + 16000.0 / 700.0);
    double m = mlo + (mhi - mlo) * (double)i / 129.0;
    return 700.0 * (pow(10.0, m / 2595.0) - 1.0);
}

// 9 blocks: 0-7 window slices, 8 = per-mel CSR build.
__global__ __launch_bounds__(256) void init_tables(float* __restrict__ ws) {
    const int tid = threadIdx.x;
    const int blk = blockIdx.x;
    if (blk < 8) {
        int i = blk * 256 + tid;
        double w = 0.5 - 0.5 * cos(2.0 * PI_D * (double)i / (double)NFFT);
        ws[OFF_WIN + i] = (float)w;
        return;
    }
    if (tid >= NMELS) return;
    const int m = tid;
    double fp0 = melpt(m), fp1 = melpt(m + 1), fp2 = melpt(m + 2);
    int* kk = (int*)(ws + OFF_KK);
    float* wwt = ws + OFF_WW;
    int k0 = (int)(fp0 / 15.625); if (k0 < 1) k0 = 1;
    int k1 = (int)(fp2 / 15.625) + 1; if (k1 > 1023) k1 = 1023;
    int cnt = 0;
    for (int k = k0; k <= k1; k++) {
        double f = (double)k * 15.625;
        double down = (f - fp0) / (fp1 - fp0);
        double up   = (fp2 - f) / (fp2 - fp1);
        double w = down < up ? down : up;
        if (w > 0.0 && cnt < 64) {
            kk[cnt * NMELS + m] = k;
            wwt[cnt * NMELS + m] = (float)w;
            cnt++;
        }
    }
    ((int*)(ws + OFF_LEN))[m] = cnt;
    for (int e = cnt; e < 65; e++) {
        kk[e * NMELS + m] = 0;
        wwt[e * NMELS + m] = 0.f;
    }
}

// 4-point DFT on slots (i0..i3).
__device__ __forceinline__ void fft4s(float* yr, float* yi, int i0, int i1, int i2, int i3) {
    float t0r = yr[i0] + yr[i2], t0i = yi[i0] + yi[i2];
    float t1r = yr[i0] - yr[i2], t1i = yi[i0] - yi[i2];
    float t2r = yr[i1] + yr[i3], t2i = yi[i1] + yi[i3];
    float t3r = yr[i1] - yr[i3], t3i = yi[i1] - yi[i3];
    yr[i0] = t0r + t2r; yi[i0] = t0i + t2i;
    yr[i1] = t1r + t3i; yi[i1] = t1i - t3r;   // out1 = t1 - i*t3
    yr[i2] = t0r - t2r; yi[i2] = t0i - t2i;
    yr[i3] = t1r - t3i; yi[i3] = t1i + t3r;   // out3 = t1 + i*t3
}

// FFT-16 (natural input in slots 0..15). Output: slot s holds OUT[SW4(s)].
__device__ __forceinline__ void fft16(float* yr, float* yi) {
    fft4s(yr, yi, 0, 4, 8, 12);
    fft4s(yr, yi, 1, 5, 9, 13);
    fft4s(yr, yi, 2, 6, 10, 14);
    fft4s(yr, yi, 3, 7, 11, 15);
    CMULC(yr[5],  yi[5],   0.92387953f, -0.38268343f);  // W1
    CMULC(yr[9],  yi[9],   0.70710678f, -0.70710678f);  // W2
    CMULC(yr[13], yi[13],  0.38268343f, -0.92387953f);  // W3
    CMULC(yr[6],  yi[6],   0.70710678f, -0.70710678f);  // W2
    { float _t = yr[10]; yr[10] = yi[10]; yi[10] = -_t; } // W4 = -i
    CMULC(yr[14], yi[14], -0.70710678f, -0.70710678f);  // W6
    CMULC(yr[7],  yi[7],   0.38268343f, -0.92387953f);  // W3
    CMULC(yr[11], yi[11], -0.70710678f, -0.70710678f);  // W6
    CMULC(yr[15], yi[15], -0.92387953f,  0.38268343f);  // W9
    fft4s(yr, yi, 0, 1, 2, 3);
    fft4s(yr, yi, 4, 5, 6, 7);
    fft4s(yr, yi, 8, 9, 10, 11);
    fft4s(yr, yi, 12, 13, 14, 15);
}

// Block = 4 waves = 4 frames. Per wave: 1024-pt FFT (16x4x16) with two
// wave-private LDS transposes, each done as re-pass + im-pass through ONE
// 1024-float buffer using 16B-chunk XOR swizzles (bank-conflict-free,
// b128-vectorized; no padding). X2 is stored transposed (16 rows x 64 cols)
// so its writes are b128 too. Untwist via shfl -> power into same buffer.
// __syncthreads -> band-balanced no-atomic mel gather (wave w = mels
// [32w,32w+32), 2 lanes/mel split even/odd CSR entries, all 4 frames).
// LDS: 4*1024*4 = 16384 B.
__global__ __launch_bounds__(256) void fft_mel_kernel(const float* __restrict__ wav,
                                                      float* __restrict__ ws) {
    __shared__ float T[4][1024];
    const int tid  = threadIdx.x;
    const int wv   = tid >> 6;
    const int lane = tid & 63;
    const int frame = blockIdx.x * 4 + wv;
    const int b = frame / NFRAMES;
    const int t = frame - b * NFRAMES;

    float yr[16], yi[16];
    const float* __restrict__ src = wav + (size_t)b * LWAV;
    const int base = t * HOP - PADW;    // even
    const float2* __restrict__ win2 = (const float2*)(ws + OFF_WIN);

    // ---- load + window: lane holds z[lane + 64c], c = 0..15 ----
    if (base >= 0 && base + NFFT <= LWAV) {
        const float2* __restrict__ s2 = (const float2*)(src + base);
#pragma unroll
        for (int c = 0; c < 16; c++) {
            int n = lane + 64 * c;
            float2 xv = s2[n];
            float2 wq = win2[n];
            yr[c] = xv.x * wq.x;
            yi[c] = xv.y * wq.y;
        }
    } else {
#pragma unroll
        for (int c = 0; c < 16; c++) {
            int n = lane + 64 * c;
            int i0 = base + 2 * n, i1 = i0 + 1;
            i0 = i0 < 0 ? -i0 : i0; i0 = i0 >= LWAV ? 2 * LWAV - 2 - i0 : i0;
            i1 = i1 < 0 ? -i1 : i1; i1 = i1 >= LWAV ? 2 * LWAV - 2 - i1 : i1;
            float2 wq = win2[n];
            yr[c] = src[i0] * wq.x;
            yi[c] = src[i1] * wq.y;
        }
    }

    // ---- S1: FFT-16 over c (slot s holds Y[SW4(s)]) ----
    fft16(yr, yi);

    // ---- T1: Y[u] *= W_1024^{lane*u} ----
    {
        float wr_, wi_;
        __sincosf(-6.13592315e-3f * (float)lane, &wi_, &wr_);
        float cr = wr_, ci = wi_;
#pragma unroll
        for (int u = 1; u < 16; u++) {
            CMULC(yr[SW4(u)], yi[SW4(u)], cr, ci);
            if (u < 15) { CMULC(cr, ci, wr_, wi_); }
        }
    }

    // ---- X1: 64x16 transpose, XOR-swizzled float4 chunks, re then im ----
    // logical M[row=lane][col=u]; chunk c (cols 4c..4c+3) stored at c^(row&3).
    // col u = 4c+j holds yr[SW4(4c+j)] = yr[4j+c].
    float* __restrict__ tb = T[wv];
    float4* __restrict__ tb4 = (float4*)tb;
    const int a = lane & 15, g = lane >> 4;
    {
#pragma unroll
        for (int c = 0; c < 4; c++) {
            float4 v; v.x = yr[c]; v.y = yr[4 + c]; v.z = yr[8 + c]; v.w = yr[12 + c];
            tb4[lane * 4 + (c ^ (lane & 3))] = v;
        }
        WVB();
#pragma unroll
        for (int bq = 0; bq < 4; bq++) {            // rows r = a+16bq, chunk g
            int r = a + 16 * bq;
            float4 v = tb4[r * 4 + (g ^ (r & 3))];
            yr[4 * bq] = v.x; yr[4 * bq + 1] = v.y; yr[4 * bq + 2] = v.z; yr[4 * bq + 3] = v.w;
        }
        WVB();
#pragma unroll
        for (int c = 0; c < 4; c++) {
            float4 v; v.x = yi[c]; v.y = yi[4 + c]; v.z = yi[8 + c]; v.w = yi[12 + c];
            tb4[lane * 4 + (c ^ (lane & 3))] = v;
        }
        WVB();
#pragma unroll
        for (int bq = 0; bq < 4; bq++) {
            int r = a + 16 * bq;
            float4 v = tb4[r * 4 + (g ^ (r & 3))];
            yi[4 * bq] = v.x; yi[4 * bq + 1] = v.y; yi[4 * bq + 2] = v.z; yi[4 * bq + 3] = v.w;
        }
        WVB();
    }

    // ---- S2: FFT-4 over b (slot 4s+m holds z_s for u=4g+m) ----
#pragma unroll
    for (int m = 0; m < 4; m++) fft4s(yr, yi, m, 4 + m, 8 + m, 12 + m);

    // ---- T2: *= W_64^{a*s} ----
    {
        float w1r, w1i;
        __sincosf(-9.81747704e-2f * (float)a, &w1i, &w1r);
        float w2r = w1r * w1r - w1i * w1i, w2i = 2.f * w1r * w1i;
        float w3r = w1r * w2r - w1i * w2i, w3i = w1r * w2i + w1i * w2r;
#pragma unroll
        for (int m = 0; m < 4; m++) {
            CMULC(yr[4 + m],  yi[4 + m],  w1r, w1i);
            CMULC(yr[8 + m],  yi[8 + m],  w2r, w2i);
            CMULC(yr[12 + m], yi[12 + m], w3r, w3i);
        }
    }

    // ---- X2: stored transposed M2t[row=a(16)][col=16s+4g+m(64)] ----
    // write: lane(a,g) row a, logical chunk 4s+g = floats yr[4s..4s+3],
    // stored at chunk (4s+g)^a. read: lane L wants col L across rows aa:
    // float at aa*64 + 4*((L>>2)^aa) + (L&3). Both conflict-free.
    {
#pragma unroll
        for (int s = 0; s < 4; s++) {
            float4 v; v.x = yr[4 * s]; v.y = yr[4 * s + 1]; v.z = yr[4 * s + 2]; v.w = yr[4 * s + 3];
            tb4[a * 16 + ((4 * s + g) ^ a)] = v;
        }
        WVB();
#pragma unroll
        for (int aa = 0; aa < 16; aa++)
            yr[aa] = tb[aa * 64 + 4 * ((lane >> 2) ^ aa) + (lane & 3)];
        WVB();
#pragma unroll
        for (int s = 0; s < 4; s++) {
            float4 v; v.x = yi[4 * s]; v.y = yi[4 * s + 1]; v.z = yi[4 * s + 2]; v.w = yi[4 * s + 3];
            tb4[a * 16 + ((4 * s + g) ^ a)] = v;
        }
        WVB();
#pragma unroll
        for (int aa = 0; aa < 16; aa++)
            yi[aa] = tb[aa * 64 + 4 * ((lane >> 2) ^ aa) + (lane & 3)];
        WVB();
    }

    // ---- S3: FFT-16 over a. Slot s holds X[lane + 64*SW4(s)] ----
    fft16(yr, yi);

    // ---- untwist + power -> tb[k] natural layout (2 words/bank: free) ----
    {
        const int pl = (64 - lane) & 63;            // partner lane
        float er, ei;
        __sincosf(-3.06796158e-3f * (float)lane, &ei, &er);   // e^{-i pi lane/1024}
        float prevR = __shfl(yr[0], pl, 64), prevI = __shfl(yi[0], pl, 64);
#pragma unroll
        for (int tt = 0; tt < 16; tt++) {
            const int sl = SW4(15 - tt);
            float curR = __shfl(yr[sl], pl, 64), curI = __shfl(yi[sl], pl, 64);
            float pr = (lane == 0) ? prevR : curR;
            float pi = (lane == 0) ? prevI : curI;
            const int ms = SW4(tt);
            float zr = yr[ms], zi = yi[ms];
            float Ar = 0.5f * (zr + pr), Ai = 0.5f * (zi - pi);
            float Or = 0.5f * (zi + pi), Oi = -0.5f * (zr - pr);
            float Xr = Ar + er * Or - ei * Oi;
            float Xi = Ai + er * Oi + ei * Or;
            tb[lane + 64 * tt] = Xr * Xr + Xi * Xi;   // power[k], k = lane+64tt
            prevR = curR; prevI = curI;
            CMULC(er, ei, 0.98078528f, -0.19509032f);   // *= e^{-i pi/16}
        }
    }
    __syncthreads();

    // ---- band-balanced mel gather: wave wv -> mels [32wv, 32wv+32) ----
    // lane pair (2j, 2j+1) splits CSR entries even/odd; each thread does
    // all 4 frames; combine via shfl_xor(1); even lane writes.
    {
        const int m = 32 * wv + (lane >> 1);
        const int p = lane & 1;
        const int L = ((const int*)(ws + OFF_LEN))[m];
        const int* __restrict__ kk = (const int*)(ws + OFF_KK);
        const float* __restrict__ wwt = ws + OFF_WW;
        const float* __restrict__ P0 = T[0];
        const float* __restrict__ P1 = T[1];
        const float* __restrict__ P2 = T[2];
        const float* __restrict__ P3 = T[3];
        float a0 = 0.f, a1 = 0.f, a2 = 0.f, a3 = 0.f;
        for (int e = p; e < L; e += 2) {
            int k = kk[e * NMELS + m];
            float w = wwt[e * NMELS + m];
            a0 = fmaf(w, P0[k], a0);
            a1 = fmaf(w, P1[k], a1);
            a2 = fmaf(w, P2[k], a2);
            a3 = fmaf(w, P3[k], a3);
        }
        a0 += __shfl_xor(a0, 1, 64);
        a1 += __shfl_xor(a1, 1, 64);
        a2 += __shfl_xor(a2, 1, 64);
        a3 += __shfl_xor(a3, 1, 64);
        if (p == 0) {
            float acc[4] = {a0, a1, a2, a3};
#pragma unroll
            for (int f = 0; f < 4; f++) {
                const int fr = blockIdx.x * 4 + f;
                const int bb = fr / NFRAMES, tt = fr - bb * NFRAMES;
                ws[OFF_MEL + (size_t)tt * (BATCH * NMELS) + bb * NMELS + m] = acc[f];
            }
        }
    }
}

// Phase 1: per-(b,chunk) local EMA with zero init; write final state.
__global__ __launch_bounds__(128) void pcen_scan1(float* __restrict__ ws) {
    const int bx = blockIdx.x;
    const int b = bx >> 4, c = bx & 15;
    const int tid = threadIdx.x;
    const int t0 = c * CHLEN;
    const int len = (c == NCH - 1) ? (NFRAMES - t0) : CHLEN;
    const float* __restrict__ mel = ws + OFF_MEL + b * NMELS + tid;
    float m = 0.f;
#pragma unroll 5
    for (int t = 0; t < len; t++) {
        float x = mel[(size_t)(t0 + t) * (BATCH * NMELS)];
        m = fmaf(0.975f, m, 0.025f * x);
    }
    ws[OFF_MFIN + (b * NCH + c) * NMELS + tid] = m;
}

// Phase 2: fold incoming state, recompute chunk, emit transposed output.
__global__ __launch_bounds__(128) void pcen_scan2(const float* __restrict__ ws,
                                                  float* __restrict__ out) {
    __shared__ float tile[CHLEN * 129];
    const int bx = blockIdx.x;
    const int b = bx >> 4, c = bx & 15;
    const int tid = threadIdx.x;
    const int t0 = c * CHLEN;
    const int len = (c == NCH - 1) ? (NFRAMES - t0) : CHLEN;
    double Apd = 1.0;
    for (int i = 0; i < CHLEN; i++) Apd *= 0.975;
    const float Ap = (float)Apd;
    float m = 0.f;
    const float* __restrict__ mfin = ws + OFF_MFIN + b * NCH * NMELS + tid;
    for (int cc = 0; cc < c; cc++) m = fmaf(Ap, m, mfin[cc * NMELS]);
    const float* __restrict__ mel = ws + OFF_MEL + b * NMELS + tid;
    for (int t = 0; t < len; t++) {
        float x = mel[(size_t)(t0 + t) * (BATCH * NMELS)];
        m = fmaf(0.975f, m, 0.025f * x);
        float d = 1e-6f + m;
        float pd = exp2f(-0.98f * __log2f(d));
        float p = sqrtf(fmaf(x, pd, 2.0f)) - 1.41421356237f;
        tile[t * 129 + tid] = p;
    }
    __syncthreads();
    if (len == CHLEN) {
        for (int idx = tid; idx < CHLEN * 128; idx += 128) {
            int row = idx / CHLEN, col = idx - row * CHLEN;   // literal divisor
            out[(size_t)(b * NMELS + row) * NFRAMES + t0 + col] = tile[col * 129 + row];
        }
    } else {
        for (int idx = tid; idx < 13 * 128; idx += 128) {
            int row = idx / 13, col = idx - row * 13;          // literal divisor
            out[(size_t)(b * NMELS + row) * NFRAMES + t0 + col] = tile[col * 129 + row];
        }
    }
}

extern "C" void kernel_launch(void* const* d_in, const int* in_sizes, int n_in,
                              void* d_out, int out_size, void* d_ws, size_t ws_size,
                              hipStream_t stream) {
    const float* wav = (const float*)d_in[0];
    float* out = (float*)d_out;
    float* ws = (float*)d_ws;
    init_tables<<<9, 256, 0, stream>>>(ws);
    fft_mel_kernel<<<(BATCH * NFRAMES) / 4, 256, 0, stream>>>(wav, ws);
    pcen_scan1<<<BATCH * NCH, 128, 0, stream>>>(ws);
    pcen_scan2<<<BATCH * NCH, 128, 0, stream>>>(ws, out);
}